// Round 4
// baseline (368.116 us; speedup 1.0000x reference)
//
#include <hip/hip_runtime.h>

// ---------------------------------------------------------------------------
// R4: (1) fused-rcp cell update: sig(o)*tanh(c) and sig(i)*tanh(g) share one
//     reciprocal each -> 5 exp + 3 rcp per element (was 5+5), fewer clamps;
//     (2) decoder 128 blocks x 4 seqs (was 32 x 16) for 4x CU coverage of the
//     serial 30-step chain. Encoder structure unchanged from R3.
// ---------------------------------------------------------------------------

typedef __attribute__((ext_vector_type(8))) short bf16x8;
typedef __attribute__((ext_vector_type(4))) float f32x4;
typedef unsigned int uint;
typedef unsigned short ushort_t;

__device__ __forceinline__ float rcp_fast(float x) { return __builtin_amdgcn_rcpf(x); }
__device__ __forceinline__ ushort_t bf_hi(float f) {
    union { float f; uint u; } v; v.f = f;
    return (ushort_t)(v.u >> 16);
}
__device__ __forceinline__ float bf_f(ushort_t h) {
    union { float f; uint u; } v; v.u = ((uint)h) << 16;
    return v.f;
}

// Fused LSTM cell update: given pre-activations (xi,xf,xg,xo) and c_prev,
// returns h and updates c. 5 exp + 3 rcp.
//   f  = 1/(1+e^-xf)
//   ig = sig(xi)*tanh(xg) = (e^{2xg}-1) * rcp((1+e^{-xi})(e^{2xg}+1))
//   c  = f*c_prev + ig
//   h  = sig(xo)*tanh(c)  = (e^{2c}-1)  * rcp((1+e^{-xo})(e^{2c}+1))
__device__ __forceinline__ float cell_update(float xi, float xf, float xg,
                                             float xo, float& c) {
    float ei = __expf(-xi);
    float ef = __expf(-xf);
    float eo = __expf(-xo);
    float eg = __expf(fminf(xg + xg, 60.0f));
    float f  = rcp_fast(1.0f + ef);
    float ig = (eg - 1.0f) * rcp_fast((1.0f + ei) * (eg + 1.0f));
    float cc = __builtin_fmaf(f, c, ig);
    c = cc;
    float e2 = __expf(fminf(cc + cc, 60.0f));
    return (e2 - 1.0f) * rcp_fast((1.0f + eo) * (e2 + 1.0f));
}

// ======================= encoder: H=64, T=50 ==============================
// 16 seqs/block; 4 waves; wave wv owns units 16wv..16wv+15 for all 4 gates.
// hb row: dwords 0..31 = h hi (64 bf16), 32..63 = h lo, pad to 76 dwords.
#define HS 76

__global__ __launch_bounds__(256, 4) void enc4_kernel(
    const float* __restrict__ ax, const float* __restrict__ nx,
    const float* __restrict__ a_wih, const float* __restrict__ a_whh,
    const float* __restrict__ a_bih, const float* __restrict__ a_bhh,
    const float* __restrict__ n_wih, const float* __restrict__ n_whh,
    const float* __restrict__ n_bih, const float* __restrict__ n_bhh,
    float* __restrict__ nh_out, float* __restrict__ ah_out)
{
    const int tid = threadIdx.x, blk = blockIdx.x;
    const bool agent = (blk >= 1024);
    const int seq0 = (agent ? (blk - 1024) : blk) * 16;
    const float* __restrict__ x   = agent ? ax : nx;
    const float* __restrict__ wih = agent ? a_wih : n_wih;
    const float* __restrict__ whh = agent ? a_whh : n_whh;
    const float* __restrict__ bih = agent ? a_bih : n_bih;
    const float* __restrict__ bhh = agent ? a_bhh : n_bhh;
    float* __restrict__ hout = agent ? ah_out : nh_out;

    const int lane = tid & 63, wv = tid >> 6;
    const int col = lane & 15, quad = lane >> 4;

    __shared__ __attribute__((aligned(16))) uint hb[2][16][HS];
    __shared__ float xs[16 * 100];

    // A fragments: Whh rows (A row = g*64 + 16wv + col, k = kt*32 + quad*8 + j)
    bf16x8 Ahi[4][2], Alo[4][2];
    #pragma unroll
    for (int g = 0; g < 4; ++g) {
        #pragma unroll
        for (int kt = 0; kt < 2; ++kt) {
            const float* p = whh + (size_t)(g * 64 + 16 * wv + col) * 64 + kt * 32 + quad * 8;
            float4 v0 = *(const float4*)p;
            float4 v1 = *(const float4*)(p + 4);
            float vv[8] = { v0.x, v0.y, v0.z, v0.w, v1.x, v1.y, v1.z, v1.w };
            bf16x8 h8, l8;
            #pragma unroll
            for (int j = 0; j < 8; ++j) {
                ushort_t hh = bf_hi(vv[j]);
                h8[j] = (short)hh;
                l8[j] = (short)bf_hi(vv[j] - bf_f(hh));
            }
            Ahi[g][kt] = h8;
            Alo[g][kt] = l8;
        }
    }

    // epilogue constants in C/D layout: row = g*64 + 16wv + 4*quad + r
    float bias[4][4], wi0[4][4], wi1[4][4];
    #pragma unroll
    for (int g = 0; g < 4; ++g) {
        #pragma unroll
        for (int r = 0; r < 4; ++r) {
            const int row = g * 64 + 16 * wv + 4 * quad + r;
            bias[g][r] = bih[row] + bhh[row];
            wi0[g][r] = wih[2 * row];
            wi1[g][r] = wih[2 * row + 1];
        }
    }

    {
        const float4* src = (const float4*)(x + (size_t)seq0 * 100);
        for (int i = tid; i < 16 * 25; i += 256) ((float4*)xs)[i] = src[i];
        for (int i = tid; i < 16 * HS; i += 256) (&hb[0][0][0])[i] = 0u;
    }
    __syncthreads();

    float c[4] = {0.f, 0.f, 0.f, 0.f};

    for (int t = 0; t < 50; ++t) {
        const int cur = t & 1, nxt = cur ^ 1;

        // acc = bias + Wih * x_t
        f32x4 acc[4];
        {
            float2 xv = *(const float2*)&xs[col * 100 + 2 * t];
            #pragma unroll
            for (int g = 0; g < 4; ++g) {
                f32x4 a;
                #pragma unroll
                for (int r = 0; r < 4; ++r)
                    a[r] = __builtin_fmaf(wi1[g][r], xv.y,
                           __builtin_fmaf(wi0[g][r], xv.x, bias[g][r]));
                acc[g] = a;
            }
        }

        // Whh @ h via 3-MFMA split
        #pragma unroll
        for (int kt = 0; kt < 2; ++kt) {
            bf16x8 Bhi = *(const bf16x8*)&hb[cur][col][kt * 16 + quad * 4];
            bf16x8 Blo = *(const bf16x8*)&hb[cur][col][32 + kt * 16 + quad * 4];
            #pragma unroll
            for (int g = 0; g < 4; ++g) {
                acc[g] = __builtin_amdgcn_mfma_f32_16x16x32_bf16(Ahi[g][kt], Bhi, acc[g], 0, 0, 0);
                acc[g] = __builtin_amdgcn_mfma_f32_16x16x32_bf16(Ahi[g][kt], Blo, acc[g], 0, 0, 0);
                acc[g] = __builtin_amdgcn_mfma_f32_16x16x32_bf16(Alo[g][kt], Bhi, acc[g], 0, 0, 0);
            }
        }

        // cell update: lane owns seq=col, units 16wv + 4quad + r
        float hv[4];
        #pragma unroll
        for (int r = 0; r < 4; ++r)
            hv[r] = cell_update(acc[0][r], acc[1][r], acc[2][r], acc[3][r], c[r]);

        {
            ushort_t h0 = bf_hi(hv[0]), h1 = bf_hi(hv[1]);
            ushort_t h2 = bf_hi(hv[2]), h3 = bf_hi(hv[3]);
            uint2 hi2, lo2;
            hi2.x = (uint)h0 | ((uint)h1 << 16);
            hi2.y = (uint)h2 | ((uint)h3 << 16);
            lo2.x = (uint)bf_hi(hv[0] - bf_f(h0)) | ((uint)bf_hi(hv[1] - bf_f(h1)) << 16);
            lo2.y = (uint)bf_hi(hv[2] - bf_f(h2)) | ((uint)bf_hi(hv[3] - bf_f(h3)) << 16);
            const int di = 8 * wv + 2 * quad;
            *(uint2*)&hb[nxt][col][di]      = hi2;
            *(uint2*)&hb[nxt][col][32 + di] = lo2;
        }
        if (t == 49) {
            #pragma unroll
            for (int r = 0; r < 4; ++r)
                hout[(size_t)(seq0 + col) * 64 + 16 * wv + 4 * quad + r] = hv[r];
        }
        __syncthreads();
    }
}

// ======================= decoder: H=128, 30 steps =========================
// 128 blocks x 4 seqs; 8 waves; wave wv owns units 16wv..16wv+15, all gates.
// hb row: dwords 0..63 = h hi (128 bf16), 64..127 = h lo, pad to 148.
// B-columns 4..15 are zero-inited dead lanes (MFMA columns are independent).
#define DS 148

__global__ __launch_bounds__(512, 2) void dec4_kernel(
    const float* __restrict__ ah, const float* __restrict__ nh,
    const float* __restrict__ d_wih, const float* __restrict__ d_whh,
    const float* __restrict__ d_bih, const float* __restrict__ d_bhh,
    const float* __restrict__ e_w, const float* __restrict__ e_b,
    float* __restrict__ out)
{
    const int tid = threadIdx.x, blk = blockIdx.x;
    const int lane = tid & 63, wv = tid >> 6;
    const int col = lane & 15, quad = lane >> 4;

    __shared__ __attribute__((aligned(16))) uint hb[2][16][DS];
    __shared__ float ews[256];

    // A fragments: (d_wih + d_whh) rows, split after fp32 sum.
    bf16x8 Ahi[4][4], Alo[4][4];
    #pragma unroll
    for (int g = 0; g < 4; ++g) {
        #pragma unroll
        for (int kt = 0; kt < 4; ++kt) {
            const size_t off = (size_t)(g * 128 + 16 * wv + col) * 128 + kt * 32 + quad * 8;
            float4 a0 = *(const float4*)(d_wih + off);
            float4 a1 = *(const float4*)(d_wih + off + 4);
            float4 b0 = *(const float4*)(d_whh + off);
            float4 b1 = *(const float4*)(d_whh + off + 4);
            float vv[8] = { a0.x + b0.x, a0.y + b0.y, a0.z + b0.z, a0.w + b0.w,
                            a1.x + b1.x, a1.y + b1.y, a1.z + b1.z, a1.w + b1.w };
            bf16x8 h8, l8;
            #pragma unroll
            for (int j = 0; j < 8; ++j) {
                ushort_t hh = bf_hi(vv[j]);
                h8[j] = (short)hh;
                l8[j] = (short)bf_hi(vv[j] - bf_f(hh));
            }
            Ahi[g][kt] = h8;
            Alo[g][kt] = l8;
        }
    }

    float bias[4][4];
    #pragma unroll
    for (int g = 0; g < 4; ++g)
        #pragma unroll
        for (int r = 0; r < 4; ++r) {
            const int row = g * 128 + 16 * wv + 4 * quad + r;
            bias[g][r] = d_bih[row] + d_bhh[row];
        }

    // h0 = [agent_emb, mean_n(neigh_emb)] for seqs 0..3; rows 4..15 zeroed.
    for (int idx = tid; idx < 16 * 128; idx += 512) {
        const int s = idx >> 7, j = idx & 127;
        float v = 0.0f;
        if (s < 4) {
            const int gseq = blk * 4 + s;
            if (j < 64) {
                v = ah[(size_t)gseq * 64 + j];
            } else {
                float acc = 0.0f;
                #pragma unroll 4
                for (int n = 0; n < 32; ++n)
                    acc += nh[(size_t)(gseq * 32 + n) * 64 + (j - 64)];
                v = acc * (1.0f / 32.0f);
            }
        }
        ushort_t hh = bf_hi(v);
        ushort_t ll = bf_hi(v - bf_f(hh));
        ushort_t* row = (ushort_t*)&hb[0][s][0];
        row[j] = hh;
        row[128 + j] = ll;
    }
    if (tid < 256) ews[tid] = e_w[tid];
    __syncthreads();

    float c[4] = {0.f, 0.f, 0.f, 0.f};
    const float eb0 = e_b[0], eb1 = e_b[1];

    for (int t = 0; t < 30; ++t) {
        const int cur = t & 1, nxt = cur ^ 1;

        f32x4 acc[4];
        #pragma unroll
        for (int g = 0; g < 4; ++g) {
            f32x4 a;
            #pragma unroll
            for (int r = 0; r < 4; ++r) a[r] = bias[g][r];
            acc[g] = a;
        }

        #pragma unroll
        for (int kt = 0; kt < 4; ++kt) {
            bf16x8 Bhi = *(const bf16x8*)&hb[cur][col][kt * 16 + quad * 4];
            bf16x8 Blo = *(const bf16x8*)&hb[cur][col][64 + kt * 16 + quad * 4];
            #pragma unroll
            for (int g = 0; g < 4; ++g) {
                acc[g] = __builtin_amdgcn_mfma_f32_16x16x32_bf16(Ahi[g][kt], Bhi, acc[g], 0, 0, 0);
                acc[g] = __builtin_amdgcn_mfma_f32_16x16x32_bf16(Ahi[g][kt], Blo, acc[g], 0, 0, 0);
                acc[g] = __builtin_amdgcn_mfma_f32_16x16x32_bf16(Alo[g][kt], Bhi, acc[g], 0, 0, 0);
            }
        }

        float hv[4];
        #pragma unroll
        for (int r = 0; r < 4; ++r)
            hv[r] = cell_update(acc[0][r], acc[1][r], acc[2][r], acc[3][r], c[r]);

        {
            ushort_t h0 = bf_hi(hv[0]), h1 = bf_hi(hv[1]);
            ushort_t h2 = bf_hi(hv[2]), h3 = bf_hi(hv[3]);
            uint2 hi2, lo2;
            hi2.x = (uint)h0 | ((uint)h1 << 16);
            hi2.y = (uint)h2 | ((uint)h3 << 16);
            lo2.x = (uint)bf_hi(hv[0] - bf_f(h0)) | ((uint)bf_hi(hv[1] - bf_f(h1)) << 16);
            lo2.y = (uint)bf_hi(hv[2] - bf_f(h2)) | ((uint)bf_hi(hv[3] - bf_f(h3)) << 16);
            const int di = 8 * wv + 2 * quad;
            *(uint2*)&hb[nxt][col][di]      = hi2;
            *(uint2*)&hb[nxt][col][64 + di] = lo2;
        }
        __syncthreads();

        // prediction head: s = tid>>5 (only s<4 live), o = (tid>>4)&1, part = tid&15
        {
            const int s = tid >> 5, o = (tid >> 4) & 1, part = tid & 15;
            if (s < 4) {
                const ushort_t* row = (const ushort_t*)&hb[nxt][s][0];
                float p = 0.0f;
                #pragma unroll
                for (int j2 = 0; j2 < 8; ++j2) {
                    const int j = part * 8 + j2;
                    float hvv = bf_f(row[j]) + bf_f(row[128 + j]);
                    p = __builtin_fmaf(hvv, ews[o * 128 + j], p);
                }
                #pragma unroll
                for (int off = 8; off > 0; off >>= 1) p += __shfl_down(p, off, 16);
                if (part == 0)
                    out[((size_t)(blk * 4 + s) * 30 + t) * 2 + o] = p + (o ? eb1 : eb0);
            }
        }
    }
}

extern "C" void kernel_launch(void* const* d_in, const int* in_sizes, int n_in,
                              void* d_out, int out_size, void* d_ws, size_t ws_size,
                              hipStream_t stream)
{
    const float* agent_traj = (const float*)d_in[0];
    const float* neigh_traj = (const float*)d_in[1];
    const float* a_wih = (const float*)d_in[2];
    const float* a_whh = (const float*)d_in[3];
    const float* a_bih = (const float*)d_in[4];
    const float* a_bhh = (const float*)d_in[5];
    const float* n_wih = (const float*)d_in[6];
    const float* n_whh = (const float*)d_in[7];
    const float* n_bih = (const float*)d_in[8];
    const float* n_bhh = (const float*)d_in[9];
    const float* d_wih = (const float*)d_in[10];
    const float* d_whh = (const float*)d_in[11];
    const float* d_bih = (const float*)d_in[12];
    const float* d_bhh = (const float*)d_in[13];
    const float* e_w   = (const float*)d_in[14];
    const float* e_b   = (const float*)d_in[15];
    float* out = (float*)d_out;

    float* nh_ws = (float*)d_ws;            // 16384*64 fp32
    float* ah_ws = nh_ws + 16384 * 64;      // 512*64 fp32

    enc4_kernel<<<dim3(1024 + 32), dim3(256), 0, stream>>>(
        agent_traj, neigh_traj,
        a_wih, a_whh, a_bih, a_bhh,
        n_wih, n_whh, n_bih, n_bhh,
        nh_ws, ah_ws);

    dec4_kernel<<<dim3(128), dim3(512), 0, stream>>>(
        ah_ws, nh_ws, d_wih, d_whh, d_bih, d_bhh, e_w, e_b, out);
}

// Round 5
// 284.695 us; speedup vs baseline: 1.2930x; 1.2930x over previous
//
#include <hip/hip_runtime.h>

// ---------------------------------------------------------------------------
// R5: fix R4 spill regression (launch_bounds back to (256,3)) and REMOVE the
// register demand instead: Wih*x + bias folded into a 3rd MFMA K-tile
// (quad-0-only fragments; x pre-staged for all 50 steps in LDS). Deletes the
// 48 scalar-const VGPRs + 32-FMA epilogue per step. Fused-rcp cell update
// kept (validated R4). Decoder = dec4 (unchanged).
// ---------------------------------------------------------------------------

typedef __attribute__((ext_vector_type(8))) short bf16x8;
typedef __attribute__((ext_vector_type(4))) float f32x4;
typedef unsigned int uint;
typedef unsigned short ushort_t;

__device__ __forceinline__ float rcp_fast(float x) { return __builtin_amdgcn_rcpf(x); }
__device__ __forceinline__ ushort_t bf_hi(float f) {
    union { float f; uint u; } v; v.f = f;
    return (ushort_t)(v.u >> 16);
}
__device__ __forceinline__ float bf_f(ushort_t h) {
    union { float f; uint u; } v; v.u = ((uint)h) << 16;
    return v.f;
}

// Fused LSTM cell update: 5 exp + 3 rcp (validated R4).
__device__ __forceinline__ float cell_update(float xi, float xf, float xg,
                                             float xo, float& c) {
    float ei = __expf(-xi);
    float ef = __expf(-xf);
    float eo = __expf(-xo);
    float eg = __expf(fminf(xg + xg, 60.0f));
    float f  = rcp_fast(1.0f + ef);
    float ig = (eg - 1.0f) * rcp_fast((1.0f + ei) * (eg + 1.0f));
    float cc = __builtin_fmaf(f, c, ig);
    c = cc;
    float e2 = __expf(fminf(cc + cc, 60.0f));
    return (e2 - 1.0f) * rcp_fast((1.0f + eo) * (e2 + 1.0f));
}

// ======================= encoder: H=64, T=50 ==============================
// 16 seqs/block; 4 waves; wave wv owns units 16wv..16wv+15 for all 4 gates.
// hb row: dwords 0..31 = h hi (64 bf16), 32..63 = h lo, pad to 76 dwords.
// 3rd K-tile (quad-0 lanes): A = [Wih_hi(2), Wih_lo(2), Wih_hi(2), b_hi, b_lo]
//                            B = [x_hi(2),   x_hi(2),   x_lo(2),   1,    1  ]
#define HS 76

__global__ __launch_bounds__(256, 3) void enc5_kernel(
    const float* __restrict__ ax, const float* __restrict__ nx,
    const float* __restrict__ a_wih, const float* __restrict__ a_whh,
    const float* __restrict__ a_bih, const float* __restrict__ a_bhh,
    const float* __restrict__ n_wih, const float* __restrict__ n_whh,
    const float* __restrict__ n_bih, const float* __restrict__ n_bhh,
    float* __restrict__ nh_out, float* __restrict__ ah_out)
{
    const int tid = threadIdx.x, blk = blockIdx.x;
    const bool agent = (blk >= 1024);
    const int seq0 = (agent ? (blk - 1024) : blk) * 16;
    const float* __restrict__ x   = agent ? ax : nx;
    const float* __restrict__ wih = agent ? a_wih : n_wih;
    const float* __restrict__ whh = agent ? a_whh : n_whh;
    const float* __restrict__ bih = agent ? a_bih : n_bih;
    const float* __restrict__ bhh = agent ? a_bhh : n_bhh;
    float* __restrict__ hout = agent ? ah_out : nh_out;

    const int lane = tid & 63, wv = tid >> 6;
    const int col = lane & 15, quad = lane >> 4;

    __shared__ __attribute__((aligned(16))) uint hb[2][16][HS];
    __shared__ __attribute__((aligned(16))) ushort_t xb[50][16][8];

    // A fragments: Whh rows (A row = g*64 + 16wv + col, k = kt*32 + quad*8 + j)
    bf16x8 Ahi[4][2], Alo[4][2];
    #pragma unroll
    for (int g = 0; g < 4; ++g) {
        #pragma unroll
        for (int kt = 0; kt < 2; ++kt) {
            const float* p = whh + (size_t)(g * 64 + 16 * wv + col) * 64 + kt * 32 + quad * 8;
            float4 v0 = *(const float4*)p;
            float4 v1 = *(const float4*)(p + 4);
            float vv[8] = { v0.x, v0.y, v0.z, v0.w, v1.x, v1.y, v1.z, v1.w };
            bf16x8 h8, l8;
            #pragma unroll
            for (int j = 0; j < 8; ++j) {
                ushort_t hh = bf_hi(vv[j]);
                h8[j] = (short)hh;
                l8[j] = (short)bf_hi(vv[j] - bf_f(hh));
            }
            Ahi[g][kt] = h8;
            Alo[g][kt] = l8;
        }
    }

    // 3rd-tile A fragments (x + bias): nonzero only on quad 0.
    bf16x8 Ax[4];
    #pragma unroll
    for (int g = 0; g < 4; ++g) {
        bf16x8 a;
        #pragma unroll
        for (int j = 0; j < 8; ++j) a[j] = 0;
        if (quad == 0) {
            const int row = g * 64 + 16 * wv + col;
            float w0 = wih[2 * row], w1 = wih[2 * row + 1];
            float b  = bih[row] + bhh[row];
            ushort_t w0h = bf_hi(w0), w1h = bf_hi(w1);
            ushort_t bh  = bf_hi(b);
            a[0] = (short)w0h;
            a[1] = (short)w1h;
            a[2] = (short)bf_hi(w0 - bf_f(w0h));
            a[3] = (short)bf_hi(w1 - bf_f(w1h));
            a[4] = (short)w0h;
            a[5] = (short)w1h;
            a[6] = (short)bh;
            a[7] = (short)bf_hi(b - bf_f(bh));
        }
        Ax[g] = a;
    }

    // stage x: all 50 steps, split hi/lo, plus the constant-1 columns
    for (int idx = tid; idx < 50 * 16; idx += 256) {
        const int t = idx >> 4, s = idx & 15;
        const float* xp = x + (size_t)(seq0 + s) * 100 + 2 * t;
        float x0 = xp[0], x1 = xp[1];
        ushort_t h0 = bf_hi(x0), h1 = bf_hi(x1);
        ushort_t* e = &xb[t][s][0];
        e[0] = h0; e[1] = h1;
        e[2] = h0; e[3] = h1;
        e[4] = bf_hi(x0 - bf_f(h0));
        e[5] = bf_hi(x1 - bf_f(h1));
        e[6] = 0x3F80; e[7] = 0x3F80;   // 1.0 in bf16
    }
    for (int i = tid; i < 16 * HS; i += 256) (&hb[0][0][0])[i] = 0u;
    __syncthreads();

    float c[4] = {0.f, 0.f, 0.f, 0.f};

    for (int t = 0; t < 50; ++t) {
        const int cur = t & 1, nxt = cur ^ 1;

        // B fragment of the 3rd tile: quad 0 reads staged x, others zero
        bf16x8 Bx;
        #pragma unroll
        for (int j = 0; j < 8; ++j) Bx[j] = 0;
        if (quad == 0) Bx = *(const bf16x8*)&xb[t][col][0];

        const f32x4 z4 = {0.f, 0.f, 0.f, 0.f};
        f32x4 acc[4];
        #pragma unroll
        for (int g = 0; g < 4; ++g)
            acc[g] = __builtin_amdgcn_mfma_f32_16x16x32_bf16(Ax[g], Bx, z4, 0, 0, 0);

        // Whh @ h via 3-MFMA split
        #pragma unroll
        for (int kt = 0; kt < 2; ++kt) {
            bf16x8 Bhi = *(const bf16x8*)&hb[cur][col][kt * 16 + quad * 4];
            bf16x8 Blo = *(const bf16x8*)&hb[cur][col][32 + kt * 16 + quad * 4];
            #pragma unroll
            for (int g = 0; g < 4; ++g) {
                acc[g] = __builtin_amdgcn_mfma_f32_16x16x32_bf16(Ahi[g][kt], Bhi, acc[g], 0, 0, 0);
                acc[g] = __builtin_amdgcn_mfma_f32_16x16x32_bf16(Ahi[g][kt], Blo, acc[g], 0, 0, 0);
                acc[g] = __builtin_amdgcn_mfma_f32_16x16x32_bf16(Alo[g][kt], Bhi, acc[g], 0, 0, 0);
            }
        }

        // cell update: lane owns seq=col, units 16wv + 4quad + r
        float hv[4];
        #pragma unroll
        for (int r = 0; r < 4; ++r)
            hv[r] = cell_update(acc[0][r], acc[1][r], acc[2][r], acc[3][r], c[r]);

        {
            ushort_t h0 = bf_hi(hv[0]), h1 = bf_hi(hv[1]);
            ushort_t h2 = bf_hi(hv[2]), h3 = bf_hi(hv[3]);
            uint2 hi2, lo2;
            hi2.x = (uint)h0 | ((uint)h1 << 16);
            hi2.y = (uint)h2 | ((uint)h3 << 16);
            lo2.x = (uint)bf_hi(hv[0] - bf_f(h0)) | ((uint)bf_hi(hv[1] - bf_f(h1)) << 16);
            lo2.y = (uint)bf_hi(hv[2] - bf_f(h2)) | ((uint)bf_hi(hv[3] - bf_f(h3)) << 16);
            const int di = 8 * wv + 2 * quad;
            *(uint2*)&hb[nxt][col][di]      = hi2;
            *(uint2*)&hb[nxt][col][32 + di] = lo2;
        }
        if (t == 49) {
            #pragma unroll
            for (int r = 0; r < 4; ++r)
                hout[(size_t)(seq0 + col) * 64 + 16 * wv + 4 * quad + r] = hv[r];
        }
        __syncthreads();
    }
}

// ======================= decoder: H=128, 30 steps =========================
// 128 blocks x 4 seqs; 8 waves; wave wv owns units 16wv..16wv+15, all gates.
#define DS 148

__global__ __launch_bounds__(512, 2) void dec5_kernel(
    const float* __restrict__ ah, const float* __restrict__ nh,
    const float* __restrict__ d_wih, const float* __restrict__ d_whh,
    const float* __restrict__ d_bih, const float* __restrict__ d_bhh,
    const float* __restrict__ e_w, const float* __restrict__ e_b,
    float* __restrict__ out)
{
    const int tid = threadIdx.x, blk = blockIdx.x;
    const int lane = tid & 63, wv = tid >> 6;
    const int col = lane & 15, quad = lane >> 4;

    __shared__ __attribute__((aligned(16))) uint hb[2][16][DS];
    __shared__ float ews[256];

    bf16x8 Ahi[4][4], Alo[4][4];
    #pragma unroll
    for (int g = 0; g < 4; ++g) {
        #pragma unroll
        for (int kt = 0; kt < 4; ++kt) {
            const size_t off = (size_t)(g * 128 + 16 * wv + col) * 128 + kt * 32 + quad * 8;
            float4 a0 = *(const float4*)(d_wih + off);
            float4 a1 = *(const float4*)(d_wih + off + 4);
            float4 b0 = *(const float4*)(d_whh + off);
            float4 b1 = *(const float4*)(d_whh + off + 4);
            float vv[8] = { a0.x + b0.x, a0.y + b0.y, a0.z + b0.z, a0.w + b0.w,
                            a1.x + b1.x, a1.y + b1.y, a1.z + b1.z, a1.w + b1.w };
            bf16x8 h8, l8;
            #pragma unroll
            for (int j = 0; j < 8; ++j) {
                ushort_t hh = bf_hi(vv[j]);
                h8[j] = (short)hh;
                l8[j] = (short)bf_hi(vv[j] - bf_f(hh));
            }
            Ahi[g][kt] = h8;
            Alo[g][kt] = l8;
        }
    }

    float bias[4][4];
    #pragma unroll
    for (int g = 0; g < 4; ++g)
        #pragma unroll
        for (int r = 0; r < 4; ++r) {
            const int row = g * 128 + 16 * wv + 4 * quad + r;
            bias[g][r] = d_bih[row] + d_bhh[row];
        }

    for (int idx = tid; idx < 16 * 128; idx += 512) {
        const int s = idx >> 7, j = idx & 127;
        float v = 0.0f;
        if (s < 4) {
            const int gseq = blk * 4 + s;
            if (j < 64) {
                v = ah[(size_t)gseq * 64 + j];
            } else {
                float acc = 0.0f;
                #pragma unroll 4
                for (int n = 0; n < 32; ++n)
                    acc += nh[(size_t)(gseq * 32 + n) * 64 + (j - 64)];
                v = acc * (1.0f / 32.0f);
            }
        }
        ushort_t hh = bf_hi(v);
        ushort_t ll = bf_hi(v - bf_f(hh));
        ushort_t* row = (ushort_t*)&hb[0][s][0];
        row[j] = hh;
        row[128 + j] = ll;
    }
    if (tid < 256) ews[tid] = e_w[tid];
    __syncthreads();

    float c[4] = {0.f, 0.f, 0.f, 0.f};
    const float eb0 = e_b[0], eb1 = e_b[1];

    for (int t = 0; t < 30; ++t) {
        const int cur = t & 1, nxt = cur ^ 1;

        f32x4 acc[4];
        #pragma unroll
        for (int g = 0; g < 4; ++g) {
            f32x4 a;
            #pragma unroll
            for (int r = 0; r < 4; ++r) a[r] = bias[g][r];
            acc[g] = a;
        }

        #pragma unroll
        for (int kt = 0; kt < 4; ++kt) {
            bf16x8 Bhi = *(const bf16x8*)&hb[cur][col][kt * 16 + quad * 4];
            bf16x8 Blo = *(const bf16x8*)&hb[cur][col][64 + kt * 16 + quad * 4];
            #pragma unroll
            for (int g = 0; g < 4; ++g) {
                acc[g] = __builtin_amdgcn_mfma_f32_16x16x32_bf16(Ahi[g][kt], Bhi, acc[g], 0, 0, 0);
                acc[g] = __builtin_amdgcn_mfma_f32_16x16x32_bf16(Ahi[g][kt], Blo, acc[g], 0, 0, 0);
                acc[g] = __builtin_amdgcn_mfma_f32_16x16x32_bf16(Alo[g][kt], Bhi, acc[g], 0, 0, 0);
            }
        }

        float hv[4];
        #pragma unroll
        for (int r = 0; r < 4; ++r)
            hv[r] = cell_update(acc[0][r], acc[1][r], acc[2][r], acc[3][r], c[r]);

        {
            ushort_t h0 = bf_hi(hv[0]), h1 = bf_hi(hv[1]);
            ushort_t h2 = bf_hi(hv[2]), h3 = bf_hi(hv[3]);
            uint2 hi2, lo2;
            hi2.x = (uint)h0 | ((uint)h1 << 16);
            hi2.y = (uint)h2 | ((uint)h3 << 16);
            lo2.x = (uint)bf_hi(hv[0] - bf_f(h0)) | ((uint)bf_hi(hv[1] - bf_f(h1)) << 16);
            lo2.y = (uint)bf_hi(hv[2] - bf_f(h2)) | ((uint)bf_hi(hv[3] - bf_f(h3)) << 16);
            const int di = 8 * wv + 2 * quad;
            *(uint2*)&hb[nxt][col][di]      = hi2;
            *(uint2*)&hb[nxt][col][64 + di] = lo2;
        }
        __syncthreads();

        {
            const int s = tid >> 5, o = (tid >> 4) & 1, part = tid & 15;
            if (s < 4) {
                const ushort_t* row = (const ushort_t*)&hb[nxt][s][0];
                float p = 0.0f;
                #pragma unroll
                for (int j2 = 0; j2 < 8; ++j2) {
                    const int j = part * 8 + j2;
                    float hvv = bf_f(row[j]) + bf_f(row[128 + j]);
                    p = __builtin_fmaf(hvv, ews[o * 128 + j], p);
                }
                #pragma unroll
                for (int off = 8; off > 0; off >>= 1) p += __shfl_down(p, off, 16);
                if (part == 0)
                    out[((size_t)(blk * 4 + s) * 30 + t) * 2 + o] = p + (o ? eb1 : eb0);
            }
        }
    }
}

extern "C" void kernel_launch(void* const* d_in, const int* in_sizes, int n_in,
                              void* d_out, int out_size, void* d_ws, size_t ws_size,
                              hipStream_t stream)
{
    const float* agent_traj = (const float*)d_in[0];
    const float* neigh_traj = (const float*)d_in[1];
    const float* a_wih = (const float*)d_in[2];
    const float* a_whh = (const float*)d_in[3];
    const float* a_bih = (const float*)d_in[4];
    const float* a_bhh = (const float*)d_in[5];
    const float* n_wih = (const float*)d_in[6];
    const float* n_whh = (const float*)d_in[7];
    const float* n_bih = (const float*)d_in[8];
    const float* n_bhh = (const float*)d_in[9];
    const float* d_wih = (const float*)d_in[10];
    const float* d_whh = (const float*)d_in[11];
    const float* d_bih = (const float*)d_in[12];
    const float* d_bhh = (const float*)d_in[13];
    const float* e_w   = (const float*)d_in[14];
    const float* e_b   = (const float*)d_in[15];
    float* out = (float*)d_out;

    float* nh_ws = (float*)d_ws;            // 16384*64 fp32
    float* ah_ws = nh_ws + 16384 * 64;      // 512*64 fp32

    enc5_kernel<<<dim3(1024 + 32), dim3(256), 0, stream>>>(
        agent_traj, neigh_traj,
        a_wih, a_whh, a_bih, a_bhh,
        n_wih, n_whh, n_bih, n_bhh,
        nh_ws, ah_ws);

    dec5_kernel<<<dim3(128), dim3(512), 0, stream>>>(
        ah_ws, nh_ws, d_wih, d_whh, d_bih, d_bhh, e_w, e_b, out);
}